// Round 5
// baseline (725.900 us; speedup 1.0000x reference)
//
#include <hip/hip_runtime.h>

typedef unsigned short u16;
typedef unsigned int u32;

// ---------- bf16 helpers (bit-level, RNE) ----------
__device__ __forceinline__ float bfl(u32 u) { union { u32 i; float f; } v; v.i = u << 16; return v.f; }
__device__ __forceinline__ float bfh(u32 u) { union { u32 i; float f; } v; v.i = u & 0xffff0000u; return v.f; }
__device__ __forceinline__ float bf2f(u16 u) { union { u32 i; float f; } v; v.i = ((u32)u) << 16; return v.f; }
__device__ __forceinline__ u16 f2bf(float f) {
    union { float f; u32 i; } v; v.f = f;
    u32 r = v.i + 0x7fffu + ((v.i >> 16) & 1u);
    return (u16)(r >> 16);
}
// HW packed f32->bf16 (RNE, same rounding as f2bf): 1 instr per 2 values
__device__ __forceinline__ u32 pk2bf(float lo, float hi) {
    u32 r;
    asm("v_cvt_pk_bf16_f32 %0, %1, %2" : "=v"(r) : "v"(lo), "v"(hi));
    return r;
}

// ---------- async global->LDS 16B ----------
typedef const __attribute__((address_space(1))) unsigned int* gas_u32;
typedef __attribute__((address_space(3))) unsigned int* las_u32;
__device__ __forceinline__ void async_cp16(const void* g, void* l) {
    __builtin_amdgcn_global_load_lds((gas_u32)g, (las_u32)l, 16, 0, 0);
}

// ---------- dtype detection (device-side, no host sync) + bcount zero ----------
__global__ void k_detect(const u32* __restrict__ xw, const int* __restrict__ eiw,
                         const void* __restrict__ ltau, int* __restrict__ flags,
                         int* __restrict__ bcount,
                         int xwords, int E, int nb) {
    __shared__ int cf32, ci64nz;
    if (threadIdx.x == 0) { cf32 = 0; ci64nz = 0; }
    __syncthreads();
    int t = threadIdx.x;             // 256 threads
    for (int i = t; i < nb; i += 256) bcount[i] = 0;
    int xs = xwords / 256;
    u32 w = xw[(size_t)t * xs];
    int e = (int)((w >> 23) & 0xFFu);
    if (e >= 100 && e <= 140) atomicAdd(&cf32, 1);
    int es = E / 256;
    int hw = eiw[2 * (size_t)t * es + 1];   // odd int32 position
    if (hw != 0) atomicAdd(&ci64nz, 1);
    __syncthreads();
    if (t == 0) {
        int f32 = (cf32 >= 192) ? 1 : 0;
        flags[0] = f32;
        flags[1] = (ci64nz == 0) ? 1 : 0;
        ((float*)flags)[2] = f32 ? ((const float*)ltau)[0] : bf2f(((const u16*)ltau)[0]);
    }
}

// ---------- fused: extract src/dst + per-block LDS histogram of bucket sizes ----------
__global__ __launch_bounds__(256) void k_edges_count(const int* __restrict__ ei,
                                                     int* __restrict__ src, int* __restrict__ dst,
                                                     int* __restrict__ bcount,
                                                     int e, int nb, const int* __restrict__ flags) {
    __shared__ int h[1024];
    int t = threadIdx.x;
    for (int i = t; i < nb; i += 256) h[i] = 0;
    __syncthreads();
    const int i64 = flags[1];
    int chunk = (e + gridDim.x - 1) / gridDim.x;
    int beg = blockIdx.x * chunk;
    int end = beg + chunk; if (end > e) end = e;
    for (int i = beg + t; i < end; i += 256) {
        int s, d;
        if (i64) { s = ei[2 * i]; d = ei[2 * (e + i)]; }   // int64 low words
        else     { s = ei[i];     d = ei[e + i]; }
        src[i] = s; dst[i] = d;
        atomicAdd(&h[d >> 7], 1);
    }
    __syncthreads();
    for (int i = t; i < nb; i += 256) { int v = h[i]; if (v) atomicAdd(&bcount[i], v); }
}

// pass 2: single-block exclusive scan of bucket counts (nb <= 8192)
__global__ __launch_bounds__(1024) void k_bscan(const int* __restrict__ bcount, int* __restrict__ bbase,
                                                int* __restrict__ bcursor, int nb) {
    int t = threadIdx.x;
    int per = (nb + 1023) >> 10;
    int b0 = t * per;
    int ls[8];
    int s = 0;
#pragma unroll
    for (int j = 0; j < 8; j++) {
        int v = 0;
        if (j < per && b0 + j < nb) v = bcount[b0 + j];
        ls[j] = v; s += v;
    }
    int lane = t & 63, w = t >> 6;
    int inc = s;
    for (int d = 1; d < 64; d <<= 1) { int u = __shfl_up(inc, d); if (lane >= d) inc += u; }
    __shared__ int wsum[16];
    __shared__ int gtot;
    if (lane == 63) wsum[w] = inc;
    __syncthreads();
    if (t == 0) { int a = 0; for (int i = 0; i < 16; i++) { int x = wsum[i]; wsum[i] = a; a += x; } gtot = a; }
    __syncthreads();
    int base = wsum[w] + inc - s;
#pragma unroll
    for (int j = 0; j < 8; j++) {
        if (j < per && b0 + j < nb) { bbase[b0 + j] = base; bcursor[b0 + j] = base; base += ls[j]; }
    }
    if (t == 0) bbase[nb] = gtot;
}

// pass 3: scatter packed (dstl<<25 | src) into bucket-sorted ebuf, block-aggregated cursors
__global__ __launch_bounds__(256) void k_bscatter(const int* __restrict__ src, const int* __restrict__ dst,
                                                  int* __restrict__ bcursor, u32* __restrict__ ebuf,
                                                  int e, int nb) {
    __shared__ int h[1024];
    __shared__ int lbase[1024];
    int t = threadIdx.x;
    for (int i = t; i < nb; i += 256) h[i] = 0;
    __syncthreads();
    int chunk = (e + gridDim.x - 1) / gridDim.x;
    int beg = blockIdx.x * chunk;
    int end = beg + chunk; if (end > e) end = e;
    for (int i = beg + t; i < end; i += 256) atomicAdd(&h[dst[i] >> 7], 1);
    __syncthreads();
    for (int i = t; i < nb; i += 256) {
        int v = h[i];
        lbase[i] = v ? atomicAdd(&bcursor[i], v) : 0;
        h[i] = 0;                    // reuse as local cursor
    }
    __syncthreads();
    for (int i = beg + t; i < end; i += 256) {
        int d = dst[i];
        int b = d >> 7;
        int p = lbase[b] + atomicAdd(&h[b], 1);
        ebuf[p] = ((u32)(d & 127) << 25) | (u32)src[i];
    }
}

// pass 4: per-bucket CSR finalize: hist+scan in LDS -> row_ptr, dinv, dense col writes
__global__ __launch_bounds__(256) void k_bcsr(const u32* __restrict__ ebuf, const int* __restrict__ bbase,
                                              int* __restrict__ row_ptr, float* __restrict__ dinv,
                                              int* __restrict__ col, int n, int nb, int e) {
    __shared__ int hist[128], sc[128], cur[128];
    int b = blockIdx.x, t = threadIdx.x;
    if (t < 128) hist[t] = 0;
    __syncthreads();
    int beg = bbase[b], end = bbase[b + 1];
    for (int j = beg + t; j < end; j += 256) atomicAdd(&hist[ebuf[j] >> 25], 1);
    __syncthreads();
    if (t < 128) sc[t] = hist[t];
    __syncthreads();
    for (int d = 1; d < 128; d <<= 1) {
        int v = 0;
        if (t < 128 && t >= d) v = sc[t - d];
        __syncthreads();
        if (t < 128) sc[t] += v;
        __syncthreads();
    }
    if (t < 128) {
        int node = (b << 7) + t;
        if (node < n) {
            int ex = sc[t] - hist[t];
            row_ptr[node] = beg + ex;
            dinv[node] = rsqrtf((float)(hist[t] + 1));   // +1 self-loop
            cur[t] = ex;
        }
    }
    if (b == 0 && t == 0) row_ptr[n] = e;
    __syncthreads();
    for (int j = beg + t; j < end; j += 256) {
        u32 ev = ebuf[j];
        int dl = (int)(ev >> 25);
        int p = atomicAdd(&cur[dl], 1);
        col[beg + p] = (int)(ev & 0x1FFFFFFu);
    }
}

// transpose weight to Bt layout, converting to bf16 if needed
__global__ void k_transpose_flex(const void* __restrict__ in, u16* __restrict__ out,
                                 int R, int C, const int* __restrict__ flags) {
    int idx = blockIdx.x * 256 + threadIdx.x;
    if (idx >= R * C) return;
    u16 v = flags[0] ? f2bf(((const float*)in)[idx]) : ((const u16*)in)[idx];
    int r = idx / C, c = idx % C;
    out[(size_t)c * R + r] = v;
}

// ---------- MFMA bf16 GEMM, B-transposed input, double-buffered LDS ----------
typedef __bf16 bf16x8 __attribute__((ext_vector_type(8)));
typedef float floatx4 __attribute__((ext_vector_type(4)));

// C[M,Nd] = A[M,Kd] @ Bt[Nd,Kd]^T
// MODE 0: scale row by dinv, store bf16.
// MODE 1: plain store at obase (flex dtype).
// MODE 2: fused softmax epilogue (requires WROWS=1, WCOLS=4, TN=1, Nd=64):
//         S=softmax(raw/tau) -> C[0..], raw logits -> C[obase..], dtype per flags.
// NOTE: launch_bounds min-waves MUST stay at 4. Round-1 experiment with
// (512,6) capped the unified VGPR+AGPR budget below the 64-reg accumulator
// -> scratch spill -> 694 MB HBM traffic/dispatch, GEMM 4x slower.
template <int WROWS, int WCOLS, int TM, int TN, int MODE, bool AFLEX, bool OFLEX>
__global__ __launch_bounds__(WROWS * WCOLS * 64, 4)
void k_gemm_bt(const void* __restrict__ A,
               const u16* __restrict__ Bt,
               void* __restrict__ C,
               const float* __restrict__ dinv,
               const int* __restrict__ flags,
               long long obase,
               int M, int Nd, int Kd) {
    constexpr int THREADS = WROWS * WCOLS * 64;
    constexpr int BM = WROWS * TM * 16;
    constexpr int BN = WCOLS * TN * 16;
    constexpr int BK = 32;
    // single LDS pool so MODE 2 can reuse it as a 64x64 f32 C-tile (16 KB)
    __shared__ u16 SMEM[2 * (BM + BN) * BK];
    auto As = (u16(*)[BM][BK])SMEM;                 // As[buf][r][k]
    auto Bs = (u16(*)[BN][BK])(SMEM + 2 * BM * BK); // Bs[buf][r][k]
    const int af32 = AFLEX ? flags[0] : 0;
    const int of32 = OFLEX ? flags[0] : 0;
    const int tid = threadIdx.x;
    const int m0 = blockIdx.y * BM;
    const int n0 = blockIdx.x * BN;
    const int lane = tid & 63;
    const int wave = tid >> 6;
    const int wm = wave / WCOLS;
    const int wn = wave % WCOLS;
    const int mrow = lane & 15;
    const int quad = lane >> 4;

    floatx4 acc[TM][TN];
#pragma unroll
    for (int i = 0; i < TM; i++)
#pragma unroll
        for (int j = 0; j < TN; j++) { floatx4 z = {0.f, 0.f, 0.f, 0.f}; acc[i][j] = z; }

    auto stage = [&](int kk, int buf) {
        if (AFLEX && af32) {
#pragma unroll
            for (int idx = tid * 8; idx < BM * BK; idx += THREADS * 8) {
                int r = idx >> 5, k = idx & 31;
                int gr = m0 + r;
                u32 t4[4] = {0, 0, 0, 0};
                if (gr < M) {
                    const float* ap = (const float*)A + (size_t)gr * Kd + kk + k;
                    float4 f0 = *(const float4*)ap;
                    float4 f1 = *(const float4*)(ap + 4);
                    t4[0] = pk2bf(f0.x, f0.y); t4[1] = pk2bf(f0.z, f0.w);
                    t4[2] = pk2bf(f1.x, f1.y); t4[3] = pk2bf(f1.z, f1.w);
                }
                *(int4*)&As[buf][r][k] = *(const int4*)t4;
            }
#pragma unroll
            for (int idx = tid * 8; idx < BN * BK; idx += THREADS * 8) {
                int r = idx >> 5, k = idx & 31;
                int4 v = *(const int4*)(Bt + (size_t)(n0 + r) * Kd + kk + k);
                *(int4*)&Bs[buf][r][k] = v;
            }
        } else {
#pragma unroll
            for (int idx = tid * 8; idx < BM * BK; idx += THREADS * 8) {
                int r = idx >> 5, k = idx & 31;
                int gr = m0 + r;
                if (gr >= M) gr = M - 1;   // clamp: garbage only reaches discarded OOB C-rows
                async_cp16((const u16*)A + (size_t)gr * Kd + kk + k, &As[buf][r][k]);
            }
#pragma unroll
            for (int idx = tid * 8; idx < BN * BK; idx += THREADS * 8) {
                int r = idx >> 5, k = idx & 31;
                async_cp16(Bt + (size_t)(n0 + r) * Kd + kk + k, &Bs[buf][r][k]);
            }
        }
    };

    const int steps = Kd / BK;
    stage(0, 0);
    for (int s = 0; s < steps; s++) {
        __syncthreads();                       // drains stage(s)
        if (s + 1 < steps) stage((s + 1) * BK, (s + 1) & 1);   // overlaps compute below
        const int b = s & 1;
        bf16x8 af[TM], bfr[TN];
#pragma unroll
        for (int i = 0; i < TM; i++)
            af[i] = *(const bf16x8*)&As[b][wm * TM * 16 + i * 16 + mrow][quad * 8];
#pragma unroll
        for (int j = 0; j < TN; j++)
            bfr[j] = *(const bf16x8*)&Bs[b][wn * TN * 16 + j * 16 + mrow][quad * 8];
#pragma unroll
        for (int i = 0; i < TM; i++)
#pragma unroll
            for (int j = 0; j < TN; j++)
                acc[i][j] = __builtin_amdgcn_mfma_f32_16x16x32_bf16(af[i], bfr[j], acc[i][j], 0, 0, 0);
    }

    if (MODE == 2) {
        // fused softmax over Nd=64 logits per row (all 64 cols live in this block)
        float inv_tau = __expf(-((const float*)flags)[2]);
        float* Ct = (float*)SMEM;              // [64][64] f32, exactly 16 KB
        __syncthreads();                       // all waves done reading As/Bs
#pragma unroll
        for (int i = 0; i < TM; i++)
#pragma unroll
            for (int r = 0; r < 4; r++) {
                int row = i * 16 + quad * 4 + r;           // wm == 0
                Ct[row * 64 + wn * 16 + mrow] = acc[i][0][r];
            }
        __syncthreads();
        for (int r16 = 0; r16 < 16; r16++) {
            int row = r16 * 4 + wave;                      // 4 waves cover 64 rows
            float raw = Ct[row * 64 + lane];
            float xv = raw * inv_tau;
            float mx = xv;
            for (int d = 32; d; d >>= 1) mx = fmaxf(mx, __shfl_xor(mx, d));
            float ev = __expf(xv - mx);
            float sm = ev;
            for (int d = 32; d; d >>= 1) sm += __shfl_xor(sm, d);
            float rr = ev / sm;
            long long grow = m0 + row;
            if (grow < M) {
                long long si = grow * 64 + lane;
                if (of32) { ((float*)C)[si] = rr; ((float*)C)[obase + si] = raw; }
                else      { ((u16*)C)[si] = f2bf(rr); ((u16*)C)[obase + si] = f2bf(raw); }
            }
        }
        return;
    }

#pragma unroll
    for (int i = 0; i < TM; i++) {
#pragma unroll
        for (int r = 0; r < 4; r++) {
            int grow = m0 + wm * TM * 16 + i * 16 + quad * 4 + r;
            if (grow < M) {
                float scale = (MODE == 0) ? dinv[grow] : 1.0f;
#pragma unroll
                for (int j = 0; j < TN; j++) {
                    int gcol = n0 + wn * TN * 16 + j * 16 + mrow;
                    float val = acc[i][j][r] * scale;
                    long long cidx = obase + (long long)grow * Nd + gcol;
                    if (OFLEX && of32) ((float*)C)[cidx] = val;
                    else               ((u16*)C)[cidx] = f2bf(val);
                }
            }
        }
    }
}

// ---------- CSR gather-aggregate: one wave per 4 nodes, half-wave uint4 rows ----------
// Round-2 proven body (8-deep main loop + 2-deep tail). 4 consecutive nodes per
// wave cuts grid 25000 -> 6250 blocks: block dispatch rate was ~205 blocks/us at
// ~0.5us/wave of work, suspected command-processor limit (occupancy 58% despite
// static limits allowing 8 waves/SIMD).
__global__ __launch_bounds__(256) void k_agg(const u16* __restrict__ g, u16* __restrict__ out,
                                             const int* __restrict__ row_ptr,
                                             const int* __restrict__ col,
                                             const float* __restrict__ dinv,
                                             const void* __restrict__ bias,
                                             const int* __restrict__ flags,
                                             int n, int do_relu) {
    int gw = (int)((blockIdx.x * 256 + threadIdx.x) >> 6);
    int lane = threadIdx.x & 63;
    int half = lane >> 5;
    int l = lane & 31;
    const u16* gp = g + (size_t)l * 8;       // 16B per lane, 32 lanes = 512B row
    // bias is node-independent: hoist
    float b0, b1, b2, b3, b4, b5, b6, b7;
    if (flags[0]) {
        const float4* bp = (const float4*)bias;
        float4 q0 = bp[2 * l], q1 = bp[2 * l + 1];
        b0 = q0.x; b1 = q0.y; b2 = q0.z; b3 = q0.w;
        b4 = q1.x; b5 = q1.y; b6 = q1.z; b7 = q1.w;
    } else {
        uint4 bv = ((const uint4*)bias)[l];
        b0 = bfl(bv.x); b1 = bfh(bv.x); b2 = bfl(bv.y); b3 = bfh(bv.y);
        b4 = bfl(bv.z); b5 = bfh(bv.z); b6 = bfl(bv.w); b7 = bfh(bv.w);
    }
    int w1 = gw * 4 + 4; if (w1 > n) w1 = n;
    for (int wid = gw * 4; wid < w1; wid++) {
        float a0 = 0.f, a1 = 0.f, a2 = 0.f, a3 = 0.f, a4 = 0.f, a5 = 0.f, a6 = 0.f, a7 = 0.f;
        if (half == 0) {                          // self term only in half 0
            uint4 rv = *(const uint4*)(gp + (size_t)wid * 256);
            a0 += bfl(rv.x); a1 += bfh(rv.x); a2 += bfl(rv.y); a3 += bfh(rv.y);
            a4 += bfl(rv.z); a5 += bfh(rv.z); a6 += bfl(rv.w); a7 += bfh(rv.w);
        }
        int beg = row_ptr[wid], end = row_ptr[wid + 1];
        for (int base = beg; base < end; base += 64) {
            int m = end - base; if (m > 64) m = 64;
            int ci = (base + lane < end) ? col[base + lane] : 0;   // 1 coalesced load / chunk
            int j = 0;
            for (; j + 16 <= m; j += 16) {        // 16 rows per group: 8 per half
                uint4 v[8];
#pragma unroll
                for (int q = 0; q < 8; q++) {
                    int s = __shfl(ci, j + 2 * q + half);
                    v[q] = *(const uint4*)(gp + (size_t)s * 256);
                }
#pragma unroll
                for (int q = 0; q < 8; q++) {
                    a0 += bfl(v[q].x); a1 += bfh(v[q].x);
                    a2 += bfl(v[q].y); a3 += bfh(v[q].y);
                    a4 += bfl(v[q].z); a5 += bfh(v[q].z);
                    a6 += bfl(v[q].w); a7 += bfh(v[q].w);
                }
            }
            for (; j < m; j += 2) {               // tail: 2 rows/iter (one per half)
                int idx = j + half;
                int s = __shfl(ci, idx < m ? idx : j);
                uint4 v = *(const uint4*)(gp + (size_t)s * 256);
                if (idx < m) {
                    a0 += bfl(v.x); a1 += bfh(v.x); a2 += bfl(v.y); a3 += bfh(v.y);
                    a4 += bfl(v.z); a5 += bfh(v.z); a6 += bfl(v.w); a7 += bfh(v.w);
                }
            }
        }
        // cross-half combine: both halves end with the full sum
        a0 += __shfl_xor(a0, 32); a1 += __shfl_xor(a1, 32);
        a2 += __shfl_xor(a2, 32); a3 += __shfl_xor(a3, 32);
        a4 += __shfl_xor(a4, 32); a5 += __shfl_xor(a5, 32);
        a6 += __shfl_xor(a6, 32); a7 += __shfl_xor(a7, 32);
        if (half == 0) {
            float dv = dinv[wid];
            float c0 = a0 * dv + b0, c1 = a1 * dv + b1, c2 = a2 * dv + b2, c3 = a3 * dv + b3;
            float c4 = a4 * dv + b4, c5 = a5 * dv + b5, c6 = a6 * dv + b6, c7 = a7 * dv + b7;
            if (do_relu) {
                c0 = fmaxf(c0, 0.f); c1 = fmaxf(c1, 0.f); c2 = fmaxf(c2, 0.f); c3 = fmaxf(c3, 0.f);
                c4 = fmaxf(c4, 0.f); c5 = fmaxf(c5, 0.f); c6 = fmaxf(c6, 0.f); c7 = fmaxf(c7, 0.f);
            }
            uint4 o;
            o.x = (u32)f2bf(c0) | ((u32)f2bf(c1) << 16);
            o.y = (u32)f2bf(c2) | ((u32)f2bf(c3) << 16);
            o.z = (u32)f2bf(c4) | ((u32)f2bf(c5) << 16);
            o.w = (u32)f2bf(c6) | ((u32)f2bf(c7) << 16);
            *(uint4*)(out + (size_t)wid * 256 + (size_t)l * 8) = o;
        }
    }
}

extern "C" void kernel_launch(void* const* d_in, const int* in_sizes, int n_in,
                              void* d_out, int out_size, void* d_ws, size_t ws_size,
                              hipStream_t stream) {
    const void* x    = d_in[0];
    const int*  ei   = (const int*)d_in[1];
    const void* W1   = d_in[2];
    const void* b1   = d_in[3];
    const void* W2   = d_in[4];
    const void* b2   = d_in[5];
    const void* Wk   = d_in[6];
    const void* ltau = d_in[7];
    const int D = 512, H = 256, K = 64;
    const int N = in_sizes[0] / D;
    const int E = in_sizes[1] / 2;
    const long long NK = (long long)N * K;
    const int nb = (N + 127) >> 7;           // 128 dst per bucket

    // ---- workspace: two big ping-pong buffers + flags + scratch ----
    // (scratch moved out of d_out: MODE-2 GEMM3 now writes the S-region while
    //  other blocks still read Bt/dinv -> d_out scratch would race)
    u16* g = (u16*)d_ws;                      // N*H bf16 = 51.2 MB
    u16* h = g + (size_t)N * H;               // N*H bf16 = 51.2 MB
    int* flags = (int*)(h + (size_t)N * H);   // 256 B
    // prep-phase overlays inside g (dead before GEMM1 writes g)
    int* srcv = (int*)g;
    int* dstv = srcv + E;
    u32* ebuf = (u32*)(dstv + E);

    size_t ooff = 0;
    char* wsbase = (char*)(flags + 64);
    auto oalloc = [&](size_t bytes) -> char* {
        char* p = wsbase + ooff;
        ooff += (bytes + 255) & ~(size_t)255;
        return p;
    };
    int*   col     = (int*)oalloc((size_t)E * 4);
    float* dinv    = (float*)oalloc((size_t)N * 4);
    int*   row_ptr = (int*)oalloc((size_t)(N + 1) * 4);
    int*   bcount  = (int*)oalloc((size_t)nb * 4);
    int*   bbase   = (int*)oalloc((size_t)(nb + 1) * 4);
    int*   bcursor = (int*)oalloc((size_t)nb * 4);
    u16*   W1t     = (u16*)oalloc((size_t)D * H * 2);
    u16*   W2t     = (u16*)oalloc((size_t)H * H * 2);
    u16*   Wkt     = (u16*)oalloc((size_t)H * K * 2);
    // ws use: 102.4 MB buffers + ~7.7 MB scratch << ws_size (~800 MB)

    auto g256 = [](long long n) { return (int)((n + 255) / 256); };

    k_detect<<<1, 256, 0, stream>>>((const u32*)x, ei, ltau, flags, bcount, in_sizes[0] / 2, E, nb);
    k_edges_count<<<256, 256, 0, stream>>>(ei, srcv, dstv, bcount, E, nb, flags);
    k_bscan<<<1, 1024, 0, stream>>>(bcount, bbase, bcursor, nb);
    k_bscatter<<<256, 256, 0, stream>>>(srcv, dstv, bcursor, ebuf, E, nb);
    k_bcsr<<<nb, 256, 0, stream>>>(ebuf, bbase, row_ptr, dinv, col, N, nb, E);

    k_transpose_flex<<<g256((long long)D * H), 256, 0, stream>>>(W1, W1t, D, H, flags);
    k_transpose_flex<<<g256((long long)H * H), 256, 0, stream>>>(W2, W2t, H, H, flags);
    k_transpose_flex<<<g256((long long)H * K), 256, 0, stream>>>(Wk, Wkt, H, K, flags);

    const int m64 = (N + 63) / 64;
    const long long aggw = ((long long)N + 3) / 4;   // 4 nodes per wave
    // layer 1: g = dinv ⊙ (x @ W1)   64x256 tile, 40KB LDS dbuf, 4 blocks/CU
    k_gemm_bt<1, 4, 4, 4, 0, true, false>
        <<<dim3(1, m64), 256, 0, stream>>>(x, W1t, g, dinv, flags, 0, N, H, D);
    k_agg<<<g256(aggw * 64), 256, 0, stream>>>(g, h, row_ptr, col, dinv, b1, flags, N, 1);
    // layer 2: g = dinv ⊙ (h @ W2)
    k_gemm_bt<1, 4, 4, 4, 0, false, false>
        <<<dim3(1, m64), 256, 0, stream>>>(h, W2t, g, dinv, flags, 0, N, H, H);
    k_agg<<<g256(aggw * 64), 256, 0, stream>>>(g, h, row_ptr, col, dinv, b2, flags, N, 0);
    // logits + fused softmax -> d_out (S at 0, raw logits at NK), dtype per flags
    k_gemm_bt<1, 4, 4, 1, 2, false, true>
        <<<dim3(1, m64), 256, 0, stream>>>(h, Wkt, d_out, dinv, flags, NK, N, K, H);
}

// Round 7
// 711.022 us; speedup vs baseline: 1.0209x; 1.0209x over previous
//
#include <hip/hip_runtime.h>

typedef unsigned short u16;
typedef unsigned int u32;

// ---------- bf16 helpers (bit-level, RNE) ----------
__device__ __forceinline__ float bfl(u32 u) { union { u32 i; float f; } v; v.i = u << 16; return v.f; }
__device__ __forceinline__ float bfh(u32 u) { union { u32 i; float f; } v; v.i = u & 0xffff0000u; return v.f; }
__device__ __forceinline__ float bf2f(u16 u) { union { u32 i; float f; } v; v.i = ((u32)u) << 16; return v.f; }
__device__ __forceinline__ u16 f2bf(float f) {
    union { float f; u32 i; } v; v.f = f;
    u32 r = v.i + 0x7fffu + ((v.i >> 16) & 1u);
    return (u16)(r >> 16);
}
// HW packed f32->bf16 (RNE, same rounding as f2bf): 1 instr per 2 values
__device__ __forceinline__ u32 pk2bf(float lo, float hi) {
    u32 r;
    asm("v_cvt_pk_bf16_f32 %0, %1, %2" : "=v"(r) : "v"(lo), "v"(hi));
    return r;
}

// ---------- async global->LDS 16B ----------
typedef const __attribute__((address_space(1))) unsigned int* gas_u32;
typedef __attribute__((address_space(3))) unsigned int* las_u32;
__device__ __forceinline__ void async_cp16(const void* g, void* l) {
    __builtin_amdgcn_global_load_lds((gas_u32)g, (las_u32)l, 16, 0, 0);
}

// ---------- dtype detection (device-side, no host sync) + bcount zero ----------
__global__ void k_detect(const u32* __restrict__ xw, const int* __restrict__ eiw,
                         const void* __restrict__ ltau, int* __restrict__ flags,
                         int* __restrict__ bcount,
                         int xwords, int E, int nb) {
    __shared__ int cf32, ci64nz;
    if (threadIdx.x == 0) { cf32 = 0; ci64nz = 0; }
    __syncthreads();
    int t = threadIdx.x;             // 256 threads
    for (int i = t; i < nb; i += 256) bcount[i] = 0;
    int xs = xwords / 256;
    u32 w = xw[(size_t)t * xs];
    int e = (int)((w >> 23) & 0xFFu);
    if (e >= 100 && e <= 140) atomicAdd(&cf32, 1);
    int es = E / 256;
    int hw = eiw[2 * (size_t)t * es + 1];   // odd int32 position
    if (hw != 0) atomicAdd(&ci64nz, 1);
    __syncthreads();
    if (t == 0) {
        int f32 = (cf32 >= 192) ? 1 : 0;
        flags[0] = f32;
        flags[1] = (ci64nz == 0) ? 1 : 0;
        ((float*)flags)[2] = f32 ? ((const float*)ltau)[0] : bf2f(((const u16*)ltau)[0]);
    }
}

// ---------- fused: extract src/dst + per-block LDS histogram of bucket sizes ----------
__global__ __launch_bounds__(256) void k_edges_count(const int* __restrict__ ei,
                                                     int* __restrict__ src, int* __restrict__ dst,
                                                     int* __restrict__ bcount,
                                                     int e, int nb, const int* __restrict__ flags) {
    __shared__ int h[1024];
    int t = threadIdx.x;
    for (int i = t; i < nb; i += 256) h[i] = 0;
    __syncthreads();
    const int i64 = flags[1];
    int chunk = (e + gridDim.x - 1) / gridDim.x;
    int beg = blockIdx.x * chunk;
    int end = beg + chunk; if (end > e) end = e;
    for (int i = beg + t; i < end; i += 256) {
        int s, d;
        if (i64) { s = ei[2 * i]; d = ei[2 * (e + i)]; }   // int64 low words
        else     { s = ei[i];     d = ei[e + i]; }
        src[i] = s; dst[i] = d;
        atomicAdd(&h[d >> 7], 1);
    }
    __syncthreads();
    for (int i = t; i < nb; i += 256) { int v = h[i]; if (v) atomicAdd(&bcount[i], v); }
}

// pass 2: single-block exclusive scan of bucket counts (nb <= 8192)
__global__ __launch_bounds__(1024) void k_bscan(const int* __restrict__ bcount, int* __restrict__ bbase,
                                                int* __restrict__ bcursor, int nb) {
    int t = threadIdx.x;
    int per = (nb + 1023) >> 10;
    int b0 = t * per;
    int ls[8];
    int s = 0;
#pragma unroll
    for (int j = 0; j < 8; j++) {
        int v = 0;
        if (j < per && b0 + j < nb) v = bcount[b0 + j];
        ls[j] = v; s += v;
    }
    int lane = t & 63, w = t >> 6;
    int inc = s;
    for (int d = 1; d < 64; d <<= 1) { int u = __shfl_up(inc, d); if (lane >= d) inc += u; }
    __shared__ int wsum[16];
    __shared__ int gtot;
    if (lane == 63) wsum[w] = inc;
    __syncthreads();
    if (t == 0) { int a = 0; for (int i = 0; i < 16; i++) { int x = wsum[i]; wsum[i] = a; a += x; } gtot = a; }
    __syncthreads();
    int base = wsum[w] + inc - s;
#pragma unroll
    for (int j = 0; j < 8; j++) {
        if (j < per && b0 + j < nb) { bbase[b0 + j] = base; bcursor[b0 + j] = base; base += ls[j]; }
    }
    if (t == 0) bbase[nb] = gtot;
}

// pass 3: scatter packed (dstl<<25 | src) into bucket-sorted ebuf, block-aggregated cursors
__global__ __launch_bounds__(256) void k_bscatter(const int* __restrict__ src, const int* __restrict__ dst,
                                                  int* __restrict__ bcursor, u32* __restrict__ ebuf,
                                                  int e, int nb) {
    __shared__ int h[1024];
    __shared__ int lbase[1024];
    int t = threadIdx.x;
    for (int i = t; i < nb; i += 256) h[i] = 0;
    __syncthreads();
    int chunk = (e + gridDim.x - 1) / gridDim.x;
    int beg = blockIdx.x * chunk;
    int end = beg + chunk; if (end > e) end = e;
    for (int i = beg + t; i < end; i += 256) atomicAdd(&h[dst[i] >> 7], 1);
    __syncthreads();
    for (int i = t; i < nb; i += 256) {
        int v = h[i];
        lbase[i] = v ? atomicAdd(&bcursor[i], v) : 0;
        h[i] = 0;                    // reuse as local cursor
    }
    __syncthreads();
    for (int i = beg + t; i < end; i += 256) {
        int d = dst[i];
        int b = d >> 7;
        int p = lbase[b] + atomicAdd(&h[b], 1);
        ebuf[p] = ((u32)(d & 127) << 25) | (u32)src[i];
    }
}

// pass 4: per-bucket CSR finalize: hist+scan in LDS -> row_ptr, dinv, dense col writes
__global__ __launch_bounds__(256) void k_bcsr(const u32* __restrict__ ebuf, const int* __restrict__ bbase,
                                              int* __restrict__ row_ptr, float* __restrict__ dinv,
                                              int* __restrict__ col, int n, int nb, int e) {
    __shared__ int hist[128], sc[128], cur[128];
    int b = blockIdx.x, t = threadIdx.x;
    if (t < 128) hist[t] = 0;
    __syncthreads();
    int beg = bbase[b], end = bbase[b + 1];
    for (int j = beg + t; j < end; j += 256) atomicAdd(&hist[ebuf[j] >> 25], 1);
    __syncthreads();
    if (t < 128) sc[t] = hist[t];
    __syncthreads();
    for (int d = 1; d < 128; d <<= 1) {
        int v = 0;
        if (t < 128 && t >= d) v = sc[t - d];
        __syncthreads();
        if (t < 128) sc[t] += v;
        __syncthreads();
    }
    if (t < 128) {
        int node = (b << 7) + t;
        if (node < n) {
            int ex = sc[t] - hist[t];
            row_ptr[node] = beg + ex;
            dinv[node] = rsqrtf((float)(hist[t] + 1));   // +1 self-loop
            cur[t] = ex;
        }
    }
    if (b == 0 && t == 0) row_ptr[n] = e;
    __syncthreads();
    for (int j = beg + t; j < end; j += 256) {
        u32 ev = ebuf[j];
        int dl = (int)(ev >> 25);
        int p = atomicAdd(&cur[dl], 1);
        col[beg + p] = (int)(ev & 0x1FFFFFFu);
    }
}

// transpose weight to Bt layout, converting to bf16 if needed
__global__ void k_transpose_flex(const void* __restrict__ in, u16* __restrict__ out,
                                 int R, int C, const int* __restrict__ flags) {
    int idx = blockIdx.x * 256 + threadIdx.x;
    if (idx >= R * C) return;
    u16 v = flags[0] ? f2bf(((const float*)in)[idx]) : ((const u16*)in)[idx];
    int r = idx / C, c = idx % C;
    out[(size_t)c * R + r] = v;
}

// ---------- MFMA bf16 GEMM, B-transposed input, double-buffered LDS ----------
typedef __bf16 bf16x8 __attribute__((ext_vector_type(8)));
typedef float floatx4 __attribute__((ext_vector_type(4)));

// C[M,Nd] = A[M,Kd] @ Bt[Nd,Kd]^T
// MODE 0: scale row by dinv, store bf16.
// MODE 1: plain store at obase (flex dtype).
// MODE 2: fused softmax epilogue (requires WROWS=1, WCOLS=4, TN=1, Nd=64):
//         S=softmax(raw/tau) -> C[0..], raw logits -> C[obase..], dtype per flags.
// launch_bounds (THREADS, 4): for WROWS=1 caps VGPR at 256/4... for WROWS=2
// (512 thr) caps at 128 -- fits the 64-reg acc + 32-reg frags (~121 total).
// Round-1's failure was (512,6) = 85-reg cap -> spill. Watch WRITE_SIZE.
template <int WROWS, int WCOLS, int TM, int TN, int MODE, bool AFLEX, bool OFLEX>
__global__ __launch_bounds__(WROWS * WCOLS * 64, 4)
void k_gemm_bt(const void* __restrict__ A,
               const u16* __restrict__ Bt,
               void* __restrict__ C,
               const float* __restrict__ dinv,
               const int* __restrict__ flags,
               long long obase,
               int M, int Nd, int Kd) {
    constexpr int THREADS = WROWS * WCOLS * 64;
    constexpr int BM = WROWS * TM * 16;
    constexpr int BN = WCOLS * TN * 16;
    constexpr int BK = 32;
    // single LDS pool so MODE 2 can reuse it as a 64x64 f32 C-tile (16 KB)
    __shared__ u16 SMEM[2 * (BM + BN) * BK];
    auto As = (u16(*)[BM][BK])SMEM;                 // As[buf][r][k]
    auto Bs = (u16(*)[BN][BK])(SMEM + 2 * BM * BK); // Bs[buf][r][k]
    const int af32 = AFLEX ? flags[0] : 0;
    const int of32 = OFLEX ? flags[0] : 0;
    const int tid = threadIdx.x;
    const int m0 = blockIdx.y * BM;
    const int n0 = blockIdx.x * BN;
    const int lane = tid & 63;
    const int wave = tid >> 6;
    const int wm = wave / WCOLS;
    const int wn = wave % WCOLS;
    const int mrow = lane & 15;
    const int quad = lane >> 4;

    floatx4 acc[TM][TN];
#pragma unroll
    for (int i = 0; i < TM; i++)
#pragma unroll
        for (int j = 0; j < TN; j++) { floatx4 z = {0.f, 0.f, 0.f, 0.f}; acc[i][j] = z; }

    auto stage = [&](int kk, int buf) {
        if (AFLEX && af32) {
#pragma unroll
            for (int idx = tid * 8; idx < BM * BK; idx += THREADS * 8) {
                int r = idx >> 5, k = idx & 31;
                int gr = m0 + r;
                u32 t4[4] = {0, 0, 0, 0};
                if (gr < M) {
                    const float* ap = (const float*)A + (size_t)gr * Kd + kk + k;
                    float4 f0 = *(const float4*)ap;
                    float4 f1 = *(const float4*)(ap + 4);
                    t4[0] = pk2bf(f0.x, f0.y); t4[1] = pk2bf(f0.z, f0.w);
                    t4[2] = pk2bf(f1.x, f1.y); t4[3] = pk2bf(f1.z, f1.w);
                }
                *(int4*)&As[buf][r][k] = *(const int4*)t4;
            }
#pragma unroll
            for (int idx = tid * 8; idx < BN * BK; idx += THREADS * 8) {
                int r = idx >> 5, k = idx & 31;
                int4 v = *(const int4*)(Bt + (size_t)(n0 + r) * Kd + kk + k);
                *(int4*)&Bs[buf][r][k] = v;
            }
        } else {
#pragma unroll
            for (int idx = tid * 8; idx < BM * BK; idx += THREADS * 8) {
                int r = idx >> 5, k = idx & 31;
                int gr = m0 + r;
                if (gr >= M) gr = M - 1;   // clamp: garbage only reaches discarded OOB C-rows
                async_cp16((const u16*)A + (size_t)gr * Kd + kk + k, &As[buf][r][k]);
            }
#pragma unroll
            for (int idx = tid * 8; idx < BN * BK; idx += THREADS * 8) {
                int r = idx >> 5, k = idx & 31;
                async_cp16(Bt + (size_t)(n0 + r) * Kd + kk + k, &Bs[buf][r][k]);
            }
        }
    };

    const int steps = Kd / BK;
    stage(0, 0);
    for (int s = 0; s < steps; s++) {
        __syncthreads();                       // drains stage(s)
        if (s + 1 < steps) stage((s + 1) * BK, (s + 1) & 1);   // overlaps compute below
        const int b = s & 1;
        bf16x8 af[TM], bfr[TN];
#pragma unroll
        for (int i = 0; i < TM; i++)
            af[i] = *(const bf16x8*)&As[b][wm * TM * 16 + i * 16 + mrow][quad * 8];
#pragma unroll
        for (int j = 0; j < TN; j++)
            bfr[j] = *(const bf16x8*)&Bs[b][wn * TN * 16 + j * 16 + mrow][quad * 8];
#pragma unroll
        for (int i = 0; i < TM; i++)
#pragma unroll
            for (int j = 0; j < TN; j++)
                acc[i][j] = __builtin_amdgcn_mfma_f32_16x16x32_bf16(af[i], bfr[j], acc[i][j], 0, 0, 0);
    }

    if (MODE == 2) {
        // fused softmax over Nd=64 logits per row (all 64 cols live in this block)
        float inv_tau = __expf(-((const float*)flags)[2]);
        float* Ct = (float*)SMEM;              // [64][64] f32, exactly 16 KB
        __syncthreads();                       // all waves done reading As/Bs
#pragma unroll
        for (int i = 0; i < TM; i++)
#pragma unroll
            for (int r = 0; r < 4; r++) {
                int row = i * 16 + quad * 4 + r;           // wm == 0
                Ct[row * 64 + wn * 16 + mrow] = acc[i][0][r];
            }
        __syncthreads();
        for (int r16 = 0; r16 < 16; r16++) {
            int row = r16 * 4 + wave;                      // 4 waves cover 64 rows
            float raw = Ct[row * 64 + lane];
            float xv = raw * inv_tau;
            float mx = xv;
            for (int d = 32; d; d >>= 1) mx = fmaxf(mx, __shfl_xor(mx, d));
            float ev = __expf(xv - mx);
            float sm = ev;
            for (int d = 32; d; d >>= 1) sm += __shfl_xor(sm, d);
            float rr = ev / sm;
            long long grow = m0 + row;
            if (grow < M) {
                long long si = grow * 64 + lane;
                if (of32) { ((float*)C)[si] = rr; ((float*)C)[obase + si] = raw; }
                else      { ((u16*)C)[si] = f2bf(rr); ((u16*)C)[obase + si] = f2bf(raw); }
            }
        }
        return;
    }

#pragma unroll
    for (int i = 0; i < TM; i++) {
#pragma unroll
        for (int r = 0; r < 4; r++) {
            int grow = m0 + wm * TM * 16 + i * 16 + quad * 4 + r;
            if (grow < M) {
                float scale = (MODE == 0) ? dinv[grow] : 1.0f;
#pragma unroll
                for (int j = 0; j < TN; j++) {
                    int gcol = n0 + wn * TN * 16 + j * 16 + mrow;
                    float val = acc[i][j][r] * scale;
                    long long cidx = obase + (long long)grow * Nd + gcol;
                    if (OFLEX && of32) ((float*)C)[cidx] = val;
                    else               ((u16*)C)[cidx] = f2bf(val);
                }
            }
        }
    }
}

// ---------- CSR gather-aggregate: one wave per node, half-wave uint4 rows ----------
// ROUND-2 PROVEN CONFIG (122 us, 3.78 TB/s): 1 node/wave, 8-deep main loop,
// 2-deep tail. Rounds 3 (uniform 8-deep clamp) and 4/5 (4 nodes/wave) both
// REGRESSED (-7%, -6%) -- this structure is at the random-gather floor
// (~7.1 TB/s logical through L2+LLC). Do not touch without new evidence.
__global__ __launch_bounds__(256) void k_agg(const u16* __restrict__ g, u16* __restrict__ out,
                                             const int* __restrict__ row_ptr,
                                             const int* __restrict__ col,
                                             const float* __restrict__ dinv,
                                             const void* __restrict__ bias,
                                             const int* __restrict__ flags,
                                             int n, int do_relu) {
    int wid = (int)((blockIdx.x * 256 + threadIdx.x) >> 6);
    int lane = threadIdx.x & 63;
    if (wid >= n) return;
    int half = lane >> 5;
    int l = lane & 31;
    const u16* gp = g + (size_t)l * 8;       // 16B per lane, 32 lanes = 512B row
    float a0 = 0.f, a1 = 0.f, a2 = 0.f, a3 = 0.f, a4 = 0.f, a5 = 0.f, a6 = 0.f, a7 = 0.f;
    if (half == 0) {                          // self term only in half 0
        uint4 rv = *(const uint4*)(gp + (size_t)wid * 256);
        a0 += bfl(rv.x); a1 += bfh(rv.x); a2 += bfl(rv.y); a3 += bfh(rv.y);
        a4 += bfl(rv.z); a5 += bfh(rv.z); a6 += bfl(rv.w); a7 += bfh(rv.w);
    }
    int beg = row_ptr[wid], end = row_ptr[wid + 1];
    for (int base = beg; base < end; base += 64) {
        int m = end - base; if (m > 64) m = 64;
        int ci = (base + lane < end) ? col[base + lane] : 0;   // 1 coalesced load / chunk
        int j = 0;
        for (; j + 16 <= m; j += 16) {        // 16 rows per group: 8 per half
            uint4 v[8];
#pragma unroll
            for (int q = 0; q < 8; q++) {
                int s = __shfl(ci, j + 2 * q + half);
                v[q] = *(const uint4*)(gp + (size_t)s * 256);
            }
#pragma unroll
            for (int q = 0; q < 8; q++) {
                a0 += bfl(v[q].x); a1 += bfh(v[q].x);
                a2 += bfl(v[q].y); a3 += bfh(v[q].y);
                a4 += bfl(v[q].z); a5 += bfh(v[q].z);
                a6 += bfl(v[q].w); a7 += bfh(v[q].w);
            }
        }
        for (; j < m; j += 2) {               // tail: 2 rows/iter (one per half)
            int idx = j + half;
            int s = __shfl(ci, idx < m ? idx : j);
            uint4 v = *(const uint4*)(gp + (size_t)s * 256);
            if (idx < m) {
                a0 += bfl(v.x); a1 += bfh(v.x); a2 += bfl(v.y); a3 += bfh(v.y);
                a4 += bfl(v.z); a5 += bfh(v.z); a6 += bfl(v.w); a7 += bfh(v.w);
            }
        }
    }
    // cross-half combine: both halves end with the full sum
    a0 += __shfl_xor(a0, 32); a1 += __shfl_xor(a1, 32);
    a2 += __shfl_xor(a2, 32); a3 += __shfl_xor(a3, 32);
    a4 += __shfl_xor(a4, 32); a5 += __shfl_xor(a5, 32);
    a6 += __shfl_xor(a6, 32); a7 += __shfl_xor(a7, 32);
    if (half == 0) {
        float dv = dinv[wid];
        float b0, b1, b2, b3, b4, b5, b6, b7;
        if (flags[0]) {
            const float4* bp = (const float4*)bias;
            float4 q0 = bp[2 * l], q1 = bp[2 * l + 1];
            b0 = q0.x; b1 = q0.y; b2 = q0.z; b3 = q0.w;
            b4 = q1.x; b5 = q1.y; b6 = q1.z; b7 = q1.w;
        } else {
            uint4 bv = ((const uint4*)bias)[l];
            b0 = bfl(bv.x); b1 = bfh(bv.x); b2 = bfl(bv.y); b3 = bfh(bv.y);
            b4 = bfl(bv.z); b5 = bfh(bv.z); b6 = bfl(bv.w); b7 = bfh(bv.w);
        }
        a0 = a0 * dv + b0; a1 = a1 * dv + b1; a2 = a2 * dv + b2; a3 = a3 * dv + b3;
        a4 = a4 * dv + b4; a5 = a5 * dv + b5; a6 = a6 * dv + b6; a7 = a7 * dv + b7;
        if (do_relu) {
            a0 = fmaxf(a0, 0.f); a1 = fmaxf(a1, 0.f); a2 = fmaxf(a2, 0.f); a3 = fmaxf(a3, 0.f);
            a4 = fmaxf(a4, 0.f); a5 = fmaxf(a5, 0.f); a6 = fmaxf(a6, 0.f); a7 = fmaxf(a7, 0.f);
        }
        uint4 o;
        o.x = (u32)f2bf(a0) | ((u32)f2bf(a1) << 16);
        o.y = (u32)f2bf(a2) | ((u32)f2bf(a3) << 16);
        o.z = (u32)f2bf(a4) | ((u32)f2bf(a5) << 16);
        o.w = (u32)f2bf(a6) | ((u32)f2bf(a7) << 16);
        *(uint4*)(out + (size_t)wid * 256 + (size_t)l * 8) = o;
    }
}

extern "C" void kernel_launch(void* const* d_in, const int* in_sizes, int n_in,
                              void* d_out, int out_size, void* d_ws, size_t ws_size,
                              hipStream_t stream) {
    const void* x    = d_in[0];
    const int*  ei   = (const int*)d_in[1];
    const void* W1   = d_in[2];
    const void* b1   = d_in[3];
    const void* W2   = d_in[4];
    const void* b2   = d_in[5];
    const void* Wk   = d_in[6];
    const void* ltau = d_in[7];
    const int D = 512, H = 256, K = 64;
    const int N = in_sizes[0] / D;
    const int E = in_sizes[1] / 2;
    const long long NK = (long long)N * K;
    const int nb = (N + 127) >> 7;           // 128 dst per bucket

    // ---- workspace: two big ping-pong buffers + flags + scratch ----
    u16* g = (u16*)d_ws;                      // N*H bf16 = 51.2 MB
    u16* h = g + (size_t)N * H;               // N*H bf16 = 51.2 MB
    int* flags = (int*)(h + (size_t)N * H);   // 256 B
    // prep-phase overlays inside g (dead before GEMM1 writes g)
    int* srcv = (int*)g;
    int* dstv = srcv + E;
    u32* ebuf = (u32*)(dstv + E);

    size_t ooff = 0;
    char* wsbase = (char*)(flags + 64);
    auto oalloc = [&](size_t bytes) -> char* {
        char* p = wsbase + ooff;
        ooff += (bytes + 255) & ~(size_t)255;
        return p;
    };
    int*   col     = (int*)oalloc((size_t)E * 4);
    float* dinv    = (float*)oalloc((size_t)N * 4);
    int*   row_ptr = (int*)oalloc((size_t)(N + 1) * 4);
    int*   bcount  = (int*)oalloc((size_t)nb * 4);
    int*   bbase   = (int*)oalloc((size_t)(nb + 1) * 4);
    int*   bcursor = (int*)oalloc((size_t)nb * 4);
    u16*   W1t     = (u16*)oalloc((size_t)D * H * 2);
    u16*   W2t     = (u16*)oalloc((size_t)H * H * 2);
    u16*   Wkt     = (u16*)oalloc((size_t)H * K * 2);
    // ws use: 102.4 MB buffers + ~7.7 MB scratch << ws_size (~800 MB)

    auto g256 = [](long long n) { return (int)((n + 255) / 256); };

    k_detect<<<1, 256, 0, stream>>>((const u32*)x, ei, ltau, flags, bcount, in_sizes[0] / 2, E, nb);
    k_edges_count<<<256, 256, 0, stream>>>(ei, srcv, dstv, bcount, E, nb, flags);
    k_bscan<<<1, 1024, 0, stream>>>(bcount, bbase, bcursor, nb);
    k_bscatter<<<256, 256, 0, stream>>>(srcv, dstv, bcursor, ebuf, E, nb);
    k_bcsr<<<nb, 256, 0, stream>>>(ebuf, bbase, row_ptr, dinv, col, N, nb, E);

    k_transpose_flex<<<g256((long long)D * H), 256, 0, stream>>>(W1, W1t, D, H, flags);
    k_transpose_flex<<<g256((long long)H * H), 256, 0, stream>>>(W2, W2t, H, H, flags);
    k_transpose_flex<<<g256((long long)H * K), 256, 0, stream>>>(Wk, Wkt, H, K, flags);

    const int m64 = (N + 63) / 64;
    const int m128 = (N + 127) / 128;
    // layer 1: g = dinv ⊙ (x @ W1)   64x256 tile (fp32-A staging path), 4 blocks/CU
    k_gemm_bt<1, 4, 4, 4, 0, true, false>
        <<<dim3(1, m64), 256, 0, stream>>>(x, W1t, g, dinv, flags, 0, N, H, D);
    k_agg<<<g256((long long)N * 64), 256, 0, stream>>>(g, h, row_ptr, col, dinv, b1, flags, N, 1);
    // layer 2: g = dinv ⊙ (h @ W2)   128x256 tile test (async path, VGPR cap 128)
    k_gemm_bt<2, 4, 4, 4, 0, false, false>
        <<<dim3(1, m128), 512, 0, stream>>>(h, W2t, g, dinv, flags, 0, N, H, H);
    k_agg<<<g256((long long)N * 64), 256, 0, stream>>>(g, h, row_ptr, col, dinv, b2, flags, N, 0);
    // logits + fused softmax -> d_out (S at 0, raw logits at NK), dtype per flags
    k_gemm_bt<1, 4, 4, 1, 2, false, true>
        <<<dim3(1, m64), 256, 0, stream>>>(h, Wkt, d_out, dinv, flags, NK, N, K, H);
}